// Round 2
// baseline (1120.197 us; speedup 1.0000x reference)
//
#include <hip/hip_runtime.h>

#define EDGES 1000000
#define NODES 100000
#define ET 128  // edges per block

typedef short short8 __attribute__((ext_vector_type(8)));
typedef float floatx4 __attribute__((ext_vector_type(4)));

#define MFMA(a, b, c) __builtin_amdgcn_mfma_f32_16x16x32_bf16(a, b, c, 0, 0, 0)

// ws layout (bytes)
#define WS_WX1 0       // 32768: Wx1[0:128][0:128] bf16 frags, frag=(ktile*8+jtile)
#define WS_WX2 32768   // 16384: Wx2[0:128][0:64]  frags, frag=(ktile*4+itile)
#define WS_WP1 49152   // 16384: Wp1[0:64][0:128]  frags, frag=(ktile*8+jtile)
#define WS_MISC 65536  // floats: [0]=bx1[128],[128]=bx2[64],[192]=bp1[128],[320]=Wp2[128],[448]=bp2,[456]=Wx1row128[128]

__device__ __forceinline__ unsigned short f2bf(float f) {
  union { float f; unsigned int u; } c;
  c.f = f;
  unsigned int u = c.u;
  u += 0x7fffu + ((u >> 16) & 1u);
  return (unsigned short)(u >> 16);
}

__device__ __forceinline__ float fast_silu(float v) {
#if __has_builtin(__builtin_amdgcn_exp2f) && __has_builtin(__builtin_amdgcn_rcpf)
  float e = __builtin_amdgcn_exp2f(-1.44269504088896340736f * v);
  return v * __builtin_amdgcn_rcpf(1.0f + e);
#else
  return v / (1.0f + __expf(-v));
#endif
}

__global__ __launch_bounds__(256) void prep_kernel(
    const float* __restrict__ Wx1, const float* __restrict__ Wx2,
    const float* __restrict__ Wp1, const float* __restrict__ bx1,
    const float* __restrict__ bx2, const float* __restrict__ bp1,
    const float* __restrict__ Wp2, const float* __restrict__ bp2,
    unsigned char* __restrict__ ws) {
  const int t = blockIdx.x * 256 + threadIdx.x;
  const int nthr = gridDim.x * 256;

  // Wx1 (first 128 rows): tasks (n=0..127, kb=0..15)
  for (int task = t; task < 2048; task += nthr) {
    const int n = task & 127;
    const int kb = task >> 7;
    const int k0 = kb << 3;
    unsigned int d[4];
#pragma unroll
    for (int i = 0; i < 4; ++i) {
      unsigned short lo = f2bf(Wx1[(k0 + 2 * i) * 128 + n]);
      unsigned short hi = f2bf(Wx1[(k0 + 2 * i + 1) * 128 + n]);
      d[i] = (unsigned int)lo | ((unsigned int)hi << 16);
    }
    const int lane = ((kb & 3) << 4) | (n & 15);
    const int frag = ((kb >> 2) << 3) | (n >> 4);
    *(uint4*)(ws + WS_WX1 + ((size_t)(frag * 64 + lane) << 4)) =
        make_uint4(d[0], d[1], d[2], d[3]);
  }
  // Wx2 [128][64]: tasks (n=0..63, kb=0..15)
  for (int task = t; task < 1024; task += nthr) {
    const int n = task & 63;
    const int kb = task >> 6;
    const int k0 = kb << 3;
    unsigned int d[4];
#pragma unroll
    for (int i = 0; i < 4; ++i) {
      unsigned short lo = f2bf(Wx2[(k0 + 2 * i) * 64 + n]);
      unsigned short hi = f2bf(Wx2[(k0 + 2 * i + 1) * 64 + n]);
      d[i] = (unsigned int)lo | ((unsigned int)hi << 16);
    }
    const int lane = ((kb & 3) << 4) | (n & 15);
    const int frag = ((kb >> 2) << 2) | (n >> 4);
    *(uint4*)(ws + WS_WX2 + ((size_t)(frag * 64 + lane) << 4)) =
        make_uint4(d[0], d[1], d[2], d[3]);
  }
  // Wp1 [64][128]: tasks (n=0..127, kb=0..7)
  for (int task = t; task < 1024; task += nthr) {
    const int n = task & 127;
    const int kb = task >> 7;
    const int k0 = kb << 3;
    unsigned int d[4];
#pragma unroll
    for (int i = 0; i < 4; ++i) {
      unsigned short lo = f2bf(Wp1[(k0 + 2 * i) * 128 + n]);
      unsigned short hi = f2bf(Wp1[(k0 + 2 * i + 1) * 128 + n]);
      d[i] = (unsigned int)lo | ((unsigned int)hi << 16);
    }
    const int lane = ((kb & 3) << 4) | (n & 15);
    const int frag = ((kb >> 2) << 3) | (n >> 4);
    *(uint4*)(ws + WS_WP1 + ((size_t)(frag * 64 + lane) << 4)) =
        make_uint4(d[0], d[1], d[2], d[3]);
  }
  float* misc = (float*)(ws + WS_MISC);
  for (int i = t; i < 128; i += nthr) misc[i] = bx1[i];
  for (int i = t; i < 64; i += nthr) misc[128 + i] = bx2[i];
  for (int i = t; i < 128; i += nthr) misc[192 + i] = bp1[i];
  for (int i = t; i < 128; i += nthr) misc[320 + i] = Wp2[i];
  if (t == 0) misc[448] = bp2[0];
  for (int i = t; i < 128; i += nthr) misc[456 + i] = Wx1[128 * 128 + i];
}

__global__ __launch_bounds__(256, 2) void edge_kernel(
    const float* __restrict__ x, const float* __restrict__ pos,
    const int* __restrict__ ei, const unsigned char* __restrict__ ws,
    float* __restrict__ out) {
  // sFeat: B-operand frags. [etile 0..7][ktile 0..3][lane 0..63] (16B each).
  // Holds feat (k=0..127) pre-GEMM1; wave-private region is overwritten with
  // silu(h) frags (k2=j=0..127) for GEMM2.
  __shared__ uint4 sFeat[2048];  // 32 KB
  __shared__ float sRel[ET * 3];
  __shared__ float sDist[ET];
  __shared__ int sRow[ET];
  __shared__ int sCol[ET];

  const int tid = threadIdx.x;
  const int lane = tid & 63;
  const int wave = tid >> 6;
  const int q = lane >> 4;
  const int nn = lane & 15;
  const int e_base = blockIdx.x * ET;

  // ---- gather phase 0: edge indices, rel_pos, dist_sq
  if (tid < ET) {
    const int eg = e_base + tid;
    int r = 0, c = 0;
    float r0 = 0.f, r1 = 0.f, r2 = 0.f, dd = 0.f;
    if (eg < EDGES) {
      // edge_index is passed as int32 by the harness (integer -> const int*)
      r = ei[eg];
      c = ei[EDGES + eg];
      // defensive clamp: an OOB index becomes a wrong answer, not a GPU fault
      r = (r < 0) ? 0 : ((r >= NODES) ? NODES - 1 : r);
      c = (c < 0) ? 0 : ((c >= NODES) ? NODES - 1 : c);
      r0 = pos[3 * r + 0] - pos[3 * c + 0];
      r1 = pos[3 * r + 1] - pos[3 * c + 1];
      r2 = pos[3 * r + 2] - pos[3 * c + 2];
      dd = r0 * r0 + r1 * r1 + r2 * r2;
    }
    sRow[tid] = r;
    sCol[tid] = c;
    sRel[3 * tid + 0] = r0;
    sRel[3 * tid + 1] = r1;
    sRel[3 * tid + 2] = r2;
    sDist[tid] = dd;
  }
  __syncthreads();

  // ---- gather phase 1: x[row] (k 0..63) and x[col] (k 64..127) -> bf16 frags
  {
    const int e = tid & (ET - 1);
    const int p = tid >> 7;  // 0: row-part, 1: col-part
    const bool valid = (e_base + e) < EDGES;
    const int node = p ? sCol[e] : sRow[e];
    const float4* src = (const float4*)(x + (size_t)node * 64);
    const int et = e >> 4;
    const int ml = e & 15;
#pragma unroll
    for (int g = 0; g < 8; ++g) {
      float4 a = valid ? src[2 * g + 0] : make_float4(0.f, 0.f, 0.f, 0.f);
      float4 b = valid ? src[2 * g + 1] : make_float4(0.f, 0.f, 0.f, 0.f);
      unsigned int d0 = (unsigned int)f2bf(a.x) | ((unsigned int)f2bf(a.y) << 16);
      unsigned int d1 = (unsigned int)f2bf(a.z) | ((unsigned int)f2bf(a.w) << 16);
      unsigned int d2 = (unsigned int)f2bf(b.x) | ((unsigned int)f2bf(b.y) << 16);
      unsigned int d3 = (unsigned int)f2bf(b.z) | ((unsigned int)f2bf(b.w) << 16);
      const int kf = p * 64 + g * 8;
      const int kt = kf >> 5;
      const int fl = (((kf & 31) >> 3) << 4) | ml;
      sFeat[(et * 4 + kt) * 64 + fl] = make_uint4(d0, d1, d2, d3);
    }
  }
  __syncthreads();

  const uint4* wx1f = (const uint4*)(ws + WS_WX1);
  const uint4* wx2f = (const uint4*)(ws + WS_WX2);
  const uint4* wp1f = (const uint4*)(ws + WS_WP1);
  const float* misc = (const float*)(ws + WS_MISC);

  const int et0 = wave * 2;  // each wave owns etiles et0, et0+1 (32 edges)
  const floatx4 fzero = {0.f, 0.f, 0.f, 0.f};

  // GEMM1': h'[j][e] = sum_k Wx1[k][j]*feat[e][k];  phi_pos: hp'[j][e] over k<64
  floatx4 acc1[2][8], accp[2][8];
#pragma unroll
  for (int m = 0; m < 2; ++m)
#pragma unroll
    for (int j = 0; j < 8; ++j) {
      acc1[m][j] = fzero;
      accp[m][j] = fzero;
    }

#pragma unroll
  for (int kt = 0; kt < 4; ++kt) {
    const short8 b0 = __builtin_bit_cast(short8, sFeat[((et0 + 0) * 4 + kt) * 64 + lane]);
    const short8 b1 = __builtin_bit_cast(short8, sFeat[((et0 + 1) * 4 + kt) * 64 + lane]);
#pragma unroll
    for (int jt = 0; jt < 8; ++jt) {
      const short8 a = __builtin_bit_cast(short8, wx1f[(kt * 8 + jt) * 64 + lane]);
      acc1[0][jt] = MFMA(a, b0, acc1[0][jt]);
      acc1[1][jt] = MFMA(a, b1, acc1[1][jt]);
    }
    if (kt < 2) {  // x_row occupies k 0..63
#pragma unroll
      for (int jt = 0; jt < 8; ++jt) {
        const short8 a = __builtin_bit_cast(short8, wp1f[(kt * 8 + jt) * 64 + lane]);
        accp[0][jt] = MFMA(a, b0, accp[0][jt]);
        accp[1][jt] = MFMA(a, b1, accp[1][jt]);
      }
    }
  }

  // ---- phi_pos epilogue: w[e] = sum_j silu(hp+bp1[j])*Wp2[j] + bp2, then pos scatter
  float wvv[2];
#pragma unroll
  for (int m = 0; m < 2; ++m) {
    float s = 0.f;
#pragma unroll
    for (int jt = 0; jt < 8; ++jt) {
      const float4 bp = *(const float4*)(misc + 192 + jt * 16 + q * 4);
      const float4 wp = *(const float4*)(misc + 320 + jt * 16 + q * 4);
      s += fast_silu(accp[m][jt][0] + bp.x) * wp.x;
      s += fast_silu(accp[m][jt][1] + bp.y) * wp.y;
      s += fast_silu(accp[m][jt][2] + bp.z) * wp.z;
      s += fast_silu(accp[m][jt][3] + bp.w) * wp.w;
    }
    s += __shfl_xor(s, 16);
    s += __shfl_xor(s, 32);
    wvv[m] = s + misc[448];
  }
  if (q == 0) {
    float* outp = out + (size_t)NODES * 64;
#pragma unroll
    for (int m = 0; m < 2; ++m) {
      const int el = (et0 + m) * 16 + nn;
      if (e_base + el < EDGES) {
        const int c = sCol[el];
        unsafeAtomicAdd(outp + (size_t)c * 3 + 0, wvv[m] * sRel[3 * el + 0]);
        unsafeAtomicAdd(outp + (size_t)c * 3 + 1, wvv[m] * sRel[3 * el + 1]);
        unsafeAtomicAdd(outp + (size_t)c * 3 + 2, wvv[m] * sRel[3 * el + 2]);
      }
    }
  }

  // ---- epilogue 1: h = silu(acc + bx1[j] + dist*Wx1[128][j]) -> bf16 B-frags in LDS
#pragma unroll
  for (int m = 0; m < 2; ++m) {
    const int etG = et0 + m;
    const float dist = sDist[etG * 16 + nn];
#pragma unroll
    for (int jt = 0; jt < 8; ++jt) {
      const float4 bx = *(const float4*)(misc + 0 + jt * 16 + q * 4);
      const float4 wd = *(const float4*)(misc + 456 + jt * 16 + q * 4);
      const unsigned short h0 = f2bf(fast_silu(acc1[m][jt][0] + bx.x + dist * wd.x));
      const unsigned short h1 = f2bf(fast_silu(acc1[m][jt][1] + bx.y + dist * wd.y));
      const unsigned short h2 = f2bf(fast_silu(acc1[m][jt][2] + bx.z + dist * wd.z));
      const unsigned short h3 = f2bf(fast_silu(acc1[m][jt][3] + bx.w + dist * wd.w));
      const int j0 = jt * 16 + q * 4;       // 4 consecutive j, same e
      const int kt2 = j0 >> 5;
      const int lane2 = (((j0 & 31) >> 3) << 4) | nn;
      const int byteoff = (j0 & 7) << 1;    // 0 or 8
      uint2* dst = (uint2*)((char*)sFeat +
                            (((size_t)((etG * 4 + kt2) * 64 + lane2)) << 4) + byteoff);
      *dst = make_uint2((unsigned int)h0 | ((unsigned int)h1 << 16),
                        (unsigned int)h2 | ((unsigned int)h3 << 16));
    }
  }

  // ---- GEMM2': msg'[i][e] = sum_j Wx2[j][i]*h[j][e]
  floatx4 acc2[2][4];
#pragma unroll
  for (int m = 0; m < 2; ++m)
#pragma unroll
    for (int it = 0; it < 4; ++it) acc2[m][it] = fzero;

#pragma unroll
  for (int kt = 0; kt < 4; ++kt) {
    const short8 b0 = __builtin_bit_cast(short8, sFeat[((et0 + 0) * 4 + kt) * 64 + lane]);
    const short8 b1 = __builtin_bit_cast(short8, sFeat[((et0 + 1) * 4 + kt) * 64 + lane]);
#pragma unroll
    for (int it = 0; it < 4; ++it) {
      const short8 a = __builtin_bit_cast(short8, wx2f[(kt * 4 + it) * 64 + lane]);
      acc2[0][it] = MFMA(a, b0, acc2[0][it]);
      acc2[1][it] = MFMA(a, b1, acc2[1][it]);
    }
  }

  // ---- epilogue 2: + bx2[i], atomic scatter into out_x[col]
#pragma unroll
  for (int m = 0; m < 2; ++m) {
    const int el = (et0 + m) * 16 + nn;
    const bool v = (e_base + el) < EDGES;
    const int c = sCol[el];
    float* orow = out + (size_t)c * 64;
#pragma unroll
    for (int it = 0; it < 4; ++it) {
      const float4 b2 = *(const float4*)(misc + 128 + it * 16 + q * 4);
      if (v) {
        const int i0 = it * 16 + q * 4;
        unsafeAtomicAdd(orow + i0 + 0, acc2[m][it][0] + b2.x);
        unsafeAtomicAdd(orow + i0 + 1, acc2[m][it][1] + b2.y);
        unsafeAtomicAdd(orow + i0 + 2, acc2[m][it][2] + b2.z);
        unsafeAtomicAdd(orow + i0 + 3, acc2[m][it][3] + b2.w);
      }
    }
  }
}

extern "C" void kernel_launch(void* const* d_in, const int* in_sizes, int n_in,
                              void* d_out, int out_size, void* d_ws, size_t ws_size,
                              hipStream_t stream) {
  (void)in_sizes; (void)n_in; (void)ws_size;
  const float* x = (const float*)d_in[0];
  const float* pos = (const float*)d_in[1];
  const int* ei = (const int*)d_in[2];
  const float* Wx1 = (const float*)d_in[3];
  const float* bx1 = (const float*)d_in[4];
  const float* Wx2 = (const float*)d_in[5];
  const float* bx2 = (const float*)d_in[6];
  const float* Wp1 = (const float*)d_in[7];
  const float* bp1 = (const float*)d_in[8];
  const float* Wp2 = (const float*)d_in[9];
  const float* bp2 = (const float*)d_in[10];
  float* out = (float*)d_out;
  unsigned char* ws = (unsigned char*)d_ws;

  hipMemsetAsync(d_out, 0, (size_t)out_size * sizeof(float), stream);
  prep_kernel<<<16, 256, 0, stream>>>(Wx1, Wx2, Wp1, bx1, bx2, bp1, Wp2, bp2, ws);
  const int nblocks = (EDGES + ET - 1) / ET;
  edge_kernel<<<nblocks, 256, 0, stream>>>(x, pos, ei, ws, out);
}